// Round 2
// baseline (308.061 us; speedup 1.0000x reference)
//
#include <hip/hip_runtime.h>
#include <stdint.h>

#define TT 512
#define NB 128
#define EM 256
#define UN 256

typedef float floatx4 __attribute__((ext_vector_type(4)));
typedef int v8i __attribute__((ext_vector_type(8)));

#define SCALE_Q 0x7B7B7B7BU   // e8m0 123 = 2^-4 (operands stored x16)
#define SCALE_A 0x7D7D7D7DU   // e8m0 125 = 2^-2  (h stored as 4*h)

// barrier without vmcnt drain: LDS-ordered only (VMEM in flight is wave-private)
#define BAR() asm volatile("s_waitcnt lgkmcnt(0)\n\ts_barrier" ::: "memory")

__device__ inline unsigned char f2fp8(float f) {
    int pk = __builtin_amdgcn_cvt_pk_fp8_f32(f, f, 0, false);  // OCP e4m3 on gfx950
    return (unsigned char)(pk & 0xff);
}
// byte-select must be an immediate: shift word so target byte is byte 0
__device__ inline float fp8dec(uint32_t word, int sel) {
#if defined(__has_builtin)
#if __has_builtin(__builtin_amdgcn_cvt_f32_fp8)
    return __builtin_amdgcn_cvt_f32_fp8(word >> (8 * sel), 0);
#else
    unsigned char b = (word >> (8 * sel)) & 0xff;
    int s = b >> 7, e = (b >> 3) & 15, m = b & 7;
    float v = e ? ldexpf((float)(8 + m), e - 10) : ldexpf((float)m, -9);
    return s ? -v : v;
#endif
#else
    unsigned char b = (word >> (8 * sel)) & 0xff;
    int s = b >> 7, e = (b >> 3) & 15, m = b & 7;
    float v = e ? ldexpf((float)(8 + m), e - 10) : ldexpf((float)m, -9);
    return s ? -v : v;
#endif
}

// ---------------------------------------------------------------------------
// Kernel 1: blocks 0..31: W*16 -> fp8 frags (K=128 layout).
//           blocks 32..63: U*16 -> fp8 frags (same layout).
// frag[((kh*16+nt)*64+lane)*32 + j] = fp8(16*M[nt*16+(lane&15)][kh*128+(lane>>4)*32+j])
// This layout serves as EITHER MFMA operand (A/B are lane-symmetric at 16x16x128).
// ---------------------------------------------------------------------------
__global__ void k_pack(const float* __restrict__ W, const float* __restrict__ U,
                       unsigned char* __restrict__ wfrag8, unsigned char* __restrict__ ufrag8) {
    int bid = blockIdx.x;
    const float* src = (bid < 32) ? W : U;
    unsigned char* dstbase = (bid < 32) ? wfrag8 : ufrag8;
    int idx = (bid & 31) * 256 + threadIdx.x;  // 0..8191
    int jg   = idx & 3;
    int lane = (idx >> 2) & 63;
    int tile = idx >> 8;            // kh*16 + nt, 0..31
    int nt = tile & 15, kh = tile >> 4;
    int u  = nt * 16 + (lane & 15);
    int k0 = kh * 128 + (lane >> 4) * 32 + jg * 8;
    unsigned char* dst = dstbase + ((size_t)tile * 64 + lane) * 32 + jg * 8;
    #pragma unroll
    for (int j = 0; j < 8; j++) dst[j] = f2fp8(16.f * src[u * EM + k0 + j]);
}

// ---------------------------------------------------------------------------
// In-block chunk GEMM (swapped operands): A = wfrag8 tile (units as M),
// B = quantized emb rows (timesteps as N). D: col(lane&15)=timestep,
// rows(kg*4+r)=4 consecutive units -> one packed u32 per ut tile ->
// single swizzled ds_write_b32 (4-way conflict max).
// xstage word layout: word(ls, c) = ls*64 + ((c) ^ ((ls&7)<<3)), c = unit/4.
// ---------------------------------------------------------------------------
__device__ inline void gemm_burst(const unsigned char* __restrict__ wfrag8,
                                  const float4* araw, unsigned char* dst,
                                  int w, int m, int kg, int lane)
{
    // quantize this lane's emb row slices -> B-frags (x16)
    union { uint32_t d[8]; v8i v; } B[2];
    #pragma unroll
    for (int kh = 0; kh < 2; kh++) {
        #pragma unroll
        for (int d2 = 0; d2 < 8; d2++) {
            float4 f = araw[kh * 8 + d2];
            int pk = __builtin_amdgcn_cvt_pk_fp8_f32(16.f * f.x, 16.f * f.y, 0, false);
            pk     = __builtin_amdgcn_cvt_pk_fp8_f32(16.f * f.z, 16.f * f.w, pk, true);
            B[kh].d[d2] = (uint32_t)pk;
        }
    }
    const floatx4 zero4 = {0.f, 0.f, 0.f, 0.f};
    const int lsout = w * 16 + m;            // chunk-local timestep this lane outputs
    const int sw = (lsout & 7) << 3;
    #pragma unroll
    for (int ut = 0; ut < 16; ut++) {
        union { uint4 u4[2]; v8i v; } A0, A1;
        const uint4* p0 = (const uint4*)(wfrag8 + ((size_t)(ut)      * 64 + lane) * 32);
        const uint4* p1 = (const uint4*)(wfrag8 + ((size_t)(16 + ut) * 64 + lane) * 32);
        A0.u4[0] = p0[0]; A0.u4[1] = p0[1];
        A1.u4[0] = p1[0]; A1.u4[1] = p1[1];
        floatx4 acc = __builtin_amdgcn_mfma_scale_f32_16x16x128_f8f6f4(
                          A0.v, B[0].v, zero4, 0, 0, 0, SCALE_Q, 0, SCALE_Q);
        acc = __builtin_amdgcn_mfma_scale_f32_16x16x128_f8f6f4(
                          A1.v, B[1].v, acc, 0, 0, 0, SCALE_Q, 0, SCALE_Q);
        // units ut*16 + kg*4 + r, r=0..3 -> bytes 0..3 of one word
        int pk = __builtin_amdgcn_cvt_pk_fp8_f32(16.f * acc[0], 16.f * acc[1], 0, false);
        pk     = __builtin_amdgcn_cvt_pk_fp8_f32(16.f * acc[2], 16.f * acc[3], pk, true);
        int wi = (ut * 4 + kg) ^ sw;
        *(uint32_t*)(dst + (size_t)lsout * 256 + wi * 4) = (uint32_t)pk;
    }
}

// ---------------------------------------------------------------------------
// Fused RNN: 128 blocks x 256 threads, 1 block/CU. Per 64-step chunk window:
//   ls==12: load next-chunk tokens; ls==16: issue emb float4 loads (regs);
//   ls==24: MFMA burst -> xstage[xcur^1]; ls==63 end: flip xcur.
// Scan step itself is byte-identical to the proven v12 (plus read swizzle).
// ---------------------------------------------------------------------------
__global__ __launch_bounds__(256, 1) void k_rnn(
    const int* __restrict__ sent, const float* __restrict__ emb,
    const unsigned char* __restrict__ wfrag8, const unsigned char* __restrict__ ufrag8,
    const float* __restrict__ W1, const float* __restrict__ b1,
    const float* __restrict__ W2, const float* __restrict__ b2,
    float* __restrict__ out)
{
    __shared__ __align__(16) unsigned char hb8[2][256];
    __shared__ __align__(16) unsigned char xstage[2][64 * 256];   // 2 x 16 KB
    __shared__ float hid[32];
    const int t    = threadIdx.x;
    const int lane = t & 63;
    const int w    = t >> 6;
    const int kg   = lane >> 4;
    const int m    = lane & 15;
    const int b    = blockIdx.x;

    // U fp8 frags -> registers: ufr8[q][kh], tile nt = 4w+q (RNN B-operand)
    v8i ufr8[4][2];
    #pragma unroll
    for (int q = 0; q < 4; q++) {
        #pragma unroll
        for (int kh = 0; kh < 2; kh++) {
            const uint4* p = (const uint4*)(ufrag8 + ((size_t)(kh * 16 + 4 * w + q) * 64 + lane) * 32);
            union { uint4 u4[2]; v8i v; } cvt;
            cvt.u4[0] = p[0]; cvt.u4[1] = p[1];
            ufr8[q][kh] = cvt.v;
        }
    }

    // ---- prologue: chunk 0 GEMM into xstage[0]
    float4 araw[16];
    int tok = sent[b * TT + w * 16 + m];
    {
        const float* arow = emb + (size_t)tok * EM + kg * 32;
        #pragma unroll
        for (int kh = 0; kh < 2; kh++)
            #pragma unroll
            for (int d = 0; d < 8; d++)
                araw[kh * 8 + d] = *(const float4*)(arow + kh * 128 + 4 * d);
    }
    gemm_burst(wfrag8, araw, &xstage[0][0], w, m, kg, lane);

    hb8[0][t] = 0; hb8[1][t] = 0;
    __syncthreads();

    int hcur = 0, xcur = 0;
    const float c3 = -0.33333334f, c5 = 0.13333334f, c7 = -0.05396825f, c9 = 0.02186949f;
    const floatx4 zero4 = {0.f, 0.f, 0.f, 0.f};
    const int sel = lane >> 4;

    for (int s = 0; s < TT; s++) {
        const int ls = s & 63;
        int wi = (t >> 2) ^ ((ls & 7) << 3);
        uint32_t xword = *(const uint32_t*)&xstage[xcur][ls * 256 + wi * 4];
        float xf = fp8dec(xword, t & 3) * 0.0625f;   // /16

        // A-frags (fp8, 4*h): broadcast 32B reads per k-half
        const unsigned char* hc = hb8[hcur];
        union { uint4 u4[2]; v8i v; } A0, A1;
        A0.u4[0] = *(const uint4*)(hc + kg * 32);
        A0.u4[1] = *(const uint4*)(hc + kg * 32 + 16);
        A1.u4[0] = *(const uint4*)(hc + 128 + kg * 32);
        A1.u4[1] = *(const uint4*)(hc + 128 + kg * 32 + 16);

        // 4 tiles, chained K=128 x2 accumulate (proven form)
        float z[4];
        #pragma unroll
        for (int q = 0; q < 4; q++) {
            floatx4 acc = __builtin_amdgcn_mfma_scale_f32_16x16x128_f8f6f4(
                              A0.v, ufr8[q][0], zero4, 0, 0, 0, SCALE_A, 0, SCALE_Q);
            acc = __builtin_amdgcn_mfma_scale_f32_16x16x128_f8f6f4(
                              A1.v, ufr8[q][1], acc, 0, 0, 0, SCALE_A, 0, SCALE_Q);
            z[q] = acc[0];
        }

        float zz = (sel == 0) ? z[0] : (sel == 1) ? z[1] : (sel == 2) ? z[2] : z[3];
        zz += xf;

        float hn;
        if (__builtin_expect(fabsf(zz) > 0.75f, 0)) {
            float e = __expf(2.f * zz);
            hn = 1.f - 2.f * __builtin_amdgcn_rcpf(e + 1.f);
        } else {
            float x2f = zz * zz;
            float p = fmaf(x2f, c9, c7);
            p = fmaf(x2f, p, c5);
            p = fmaf(x2f, p, c3);
            hn = fmaf(zz * x2f, p, zz);
        }

        hb8[hcur ^ 1][t] = f2fp8(4.f * hn);

        // ---- next-chunk GEMM, spread across this chunk's window
        int nbase = (s & ~63) + 64;          // chunk-base of the chunk being built
        if (nbase < TT) {
            if (ls == 12) {
                tok = sent[b * TT + nbase + w * 16 + m];
            }
            if (ls == 16) {
                const float* arow = emb + (size_t)tok * EM + kg * 32;
                #pragma unroll
                for (int kh = 0; kh < 2; kh++)
                    #pragma unroll
                    for (int d = 0; d < 8; d++)
                        araw[kh * 8 + d] = *(const float4*)(arow + kh * 128 + 4 * d);
            }
            if (ls == 24) {
                gemm_burst(wfrag8, araw, &xstage[xcur ^ 1][0], w, m, kg, lane);
            }
        }
        if (ls == 63) xcur ^= 1;
        BAR();
        hcur ^= 1;
    }

    // ---- head: hidden = relu(h @ W1 + b1); logits; softmax (h = fp8/4)
    if (t < 32) {
        float a = b1[t];
        for (int k = 0; k < 256; k++) {
            uint32_t wd = *(const uint32_t*)&hb8[hcur][k & ~3];
            a += 0.25f * fp8dec(wd, k & 3) * W1[k * 32 + t];
        }
        hid[t] = fmaxf(a, 0.f);
    }
    __syncthreads();
    if (t == 0) {
        float l0 = b2[0], l1 = b2[1];
        #pragma unroll
        for (int i = 0; i < 32; i++) {
            float hv = hid[i];
            l0 += hv * W2[2 * i];
            l1 += hv * W2[2 * i + 1];
        }
        float mx2 = fmaxf(l0, l1);
        float e0 = __expf(l0 - mx2), e1 = __expf(l1 - mx2);
        float inv = 1.f / (e0 + e1);
        out[2 * b]     = e0 * inv;
        out[2 * b + 1] = e1 * inv;
    }
}

extern "C" void kernel_launch(void* const* d_in, const int* in_sizes, int n_in,
                              void* d_out, int out_size, void* d_ws, size_t ws_size,
                              hipStream_t stream) {
    const int*   sent = (const int*)d_in[0];
    const float* emb  = (const float*)d_in[1];
    const float* W    = (const float*)d_in[2];
    const float* U    = (const float*)d_in[3];
    const float* W1   = (const float*)d_in[4];
    const float* b1   = (const float*)d_in[5];
    const float* W2   = (const float*)d_in[6];
    const float* b2   = (const float*)d_in[7];
    float* out = (float*)d_out;

    unsigned char* wfrag8 = (unsigned char*)d_ws;                 // 64 KB
    unsigned char* ufrag8 = wfrag8 + (size_t)UN * EM;             // 64 KB

    k_pack<<<64, 256, 0, stream>>>(W, U, wfrag8, ufrag8);
    k_rnn<<<NB, 256, 0, stream>>>(sent, emb, wfrag8, ufrag8, W1, b1, W2, b2, out);
}